// Round 4
// baseline (258.978 us; speedup 1.0000x reference)
//
#include <hip/hip_runtime.h>
#include <hip/hip_bf16.h>

// out[n] = b + e_x[n] * sum_m exp(2*GAMMA*dot(x_n,y_m)) * c[m],
//   e_x[n] = exp(-GAMMA*||x_n||^2), c[m] = exp(-GAMMA*||y_m||^2)*W[m].
// n=16384, m=8192, d=512.
// Round 4: round 3's persistent 8-phase pipeline, but with the PROVEN sync
// mechanics: __builtin_amdgcn_s_barrier() + naked counted "s_waitcnt vmcnt(4)"
// (NO "memory" clobbers -> no compiler-inserted vmcnt(0) drains at barriers).
// This is the single-variable test of the T4-defeated theory.
//
// Workspace: Xb bf16[16384*512] @0, Yb bf16[8192*512] @16777216,
//            ex f32[16384] @25165824, cw f32[8192] @25231360.

#define GAMMA 0.002f

typedef __bf16 bf16x8 __attribute__((ext_vector_type(8)));
typedef float  f32x4  __attribute__((ext_vector_type(4)));
typedef __attribute__((address_space(3))) void lds_void_t;
typedef __attribute__((address_space(1))) const void gl_void_t;

// ---------------- prep: f32 -> bf16 + exp(-gamma*||row||^2) (xW==nullptr)
// or c[m] = exp(-gamma*||row||^2)*W[m]
__global__ __launch_bounds__(256) void prep_kernel(const float* __restrict__ src,
                                                   __bf16* __restrict__ dst,
                                                   float* __restrict__ fac,
                                                   const float* __restrict__ xW,
                                                   int nrows) {
    const int wid  = threadIdx.x >> 6;
    const int lane = threadIdx.x & 63;
    const int row  = blockIdx.x * 4 + wid;
    if (row >= nrows) return;
    const float4* s = reinterpret_cast<const float4*>(src + (size_t)row * 512);
    float4 v0 = s[lane * 2];
    float4 v1 = s[lane * 2 + 1];
    float acc = v0.x * v0.x + v0.y * v0.y + v0.z * v0.z + v0.w * v0.w
              + v1.x * v1.x + v1.y * v1.y + v1.z * v1.z + v1.w * v1.w;
    bf16x8 o;
    o[0] = (__bf16)v0.x; o[1] = (__bf16)v0.y; o[2] = (__bf16)v0.z; o[3] = (__bf16)v0.w;
    o[4] = (__bf16)v1.x; o[5] = (__bf16)v1.y; o[6] = (__bf16)v1.z; o[7] = (__bf16)v1.w;
    *reinterpret_cast<bf16x8*>(dst + (size_t)row * 512 + lane * 8) = o;
#pragma unroll
    for (int off = 32; off >= 1; off >>= 1) acc += __shfl_xor(acc, off, 64);
    if (lane == 0) {
        float e = __expf(-GAMMA * acc);
        fac[row] = xW ? e * xW[row] : e;
    }
}

__global__ void init_out(float* __restrict__ out, const float* __restrict__ b, int n) {
    int i = blockIdx.x * blockDim.x + threadIdx.x;
    if (i < n) out[i] = b[0];
}

// ---------------- LDS geometry ----------------
// A: [dbuf d][half h][row 0..127][128 B] at (d*2+h)*16384; B same at +65536.
// Granule swizzle: 16B granule g stored at col g ^ (row&7); staged linearly via
// pre-swizzled global source address (both-sides swizzle, rule #21).

#define DSR_A(d, rb, ks) (*reinterpret_cast<const bf16x8*>( \
    &smem[(aBase + (d)*32768 + (rb)*2048) ^ ((ks)*64)]))
#define DSR_B(d, cb, ks) (*reinterpret_cast<const bf16x8*>( \
    &smem[(bBase + (d)*32768 + (cb)*2048) ^ ((ks)*64)]))

// Stage one half-tile (128 rows x 64 k): this wave's 16 rows via 2 x 1KB loads.
#define STAGE(PTR, KOFF, MOFF, D, H) do { \
    __builtin_amdgcn_global_load_lds((gl_void_t*)((PTR) + (size_t)((H)*128)*512 + (KOFF)), \
        (lds_void_t*)(smem + (MOFF) + ((D)*2+(H))*16384 + swave), 16, 0, 0); \
    __builtin_amdgcn_global_load_lds((gl_void_t*)((PTR) + (size_t)((H)*128 + 8)*512 + (KOFF)), \
        (lds_void_t*)(smem + (MOFF) + ((D)*2+(H))*16384 + swave + 1024), 16, 0, 0); \
} while (0)

// Proven sync mechanics (m201/m218 template): builtin barrier, naked waitcnt.
#define BAR __builtin_amdgcn_s_barrier()
#define VM4 asm volatile("s_waitcnt vmcnt(4)")
#define VMNONE ((void)0)

#define PHASE(d, q, READB, STAGE_STMT, VMSTMT) do { \
    bf16x8 a00 = DSR_A(d, 2*(q),   0); \
    bf16x8 a01 = DSR_A(d, 2*(q),   1); \
    bf16x8 a10 = DSR_A(d, 2*(q)+1, 0); \
    bf16x8 a11 = DSR_A(d, 2*(q)+1, 1); \
    if (READB) { \
        _Pragma("unroll") \
        for (int cb = 0; cb < 4; ++cb) { \
            bfr[cb][0] = DSR_B(d, cb, 0); \
            bfr[cb][1] = DSR_B(d, cb, 1); \
        } \
    } \
    STAGE_STMT; \
    VMSTMT; \
    BAR; \
    __builtin_amdgcn_s_setprio(1); \
    _Pragma("unroll") \
    for (int cb = 0; cb < 4; ++cb) { \
        acc[2*(q)][cb]   = __builtin_amdgcn_mfma_f32_16x16x32_bf16(a00, bfr[cb][0], acc[2*(q)][cb],   0, 0, 0); \
        acc[2*(q)][cb]   = __builtin_amdgcn_mfma_f32_16x16x32_bf16(a01, bfr[cb][1], acc[2*(q)][cb],   0, 0, 0); \
        acc[2*(q)+1][cb] = __builtin_amdgcn_mfma_f32_16x16x32_bf16(a10, bfr[cb][0], acc[2*(q)+1][cb], 0, 0, 0); \
        acc[2*(q)+1][cb] = __builtin_amdgcn_mfma_f32_16x16x32_bf16(a11, bfr[cb][1], acc[2*(q)+1][cb], 0, 0, 0); \
    } \
    __builtin_amdgcn_s_setprio(0); \
    BAR; \
} while (0)

// grid: 256 blocks (1/CU), 512 threads (8 waves, 2Mx4N). Persistent over 8 tm tiles.
__global__ __launch_bounds__(512, 2) void rbf_gemm(
    const __bf16* __restrict__ Xb, const __bf16* __restrict__ Yb,
    const float* __restrict__ ex, const float* __restrict__ cw,
    float* __restrict__ out) {
    __shared__ __align__(128) char smem[131072];

    const int tid  = threadIdx.x;
    const int wid  = tid >> 6;
    const int lane = tid & 63;
    const int wr   = wid >> 2;      // 0..1 (row half)
    const int wc   = wid & 3;       // 0..3 (col quarter)

    // XCD x hosts blocks pid%8==x: tn in [x*8, x*8+8) (A stays L2-hot), tm quarter sweeps.
    const int pid  = blockIdx.x;
    const int xcd  = pid & 7;
    const int j    = pid >> 3;                 // 0..31
    const int tn   = xcd * 8 + (j & 7);        // 0..63
    const int tmQ  = j >> 3;                   // 0..3
    const int tnBase = tn * 256;

    // ds_read per-lane bases (byte offsets)
    const int rl   = lane & 15;
    const int cb0  = (((lane >> 4) ^ (lane & 7)) & 7) * 16;
    const int aBase = wr * 16384 + rl * 128 + cb0;
    const int bBase = 65536 + (wc >> 1) * 16384 + ((wc & 1) * 64 + rl) * 128 + cb0;

    // staging: per-lane pre-swizzled global offset (elems) + wave LDS window
    const int gOff  = (lane >> 3) * 512 + (((lane & 7) ^ (lane >> 3)) * 8);
    const int swave = wid * 2048;
    const __bf16* sA = Xb + (size_t)(tnBase + wid * 16) * 512 + gOff;
    const __bf16* sBcur = Yb + (size_t)(tmQ * 8 * 256 + wid * 16) * 512 + gOff;

    f32x4  acc[8][4] = {};
    float  rowsum[8][4] = {};
    bf16x8 bfr[4][2];

    const int lcol = lane & 15, lrow = lane >> 4;

    // ---- prologue (once per kernel): A(k0)->d0, B(k0)->d0, B(k1)->d1
    STAGE(sA, 0,  0,     0, 0);
    STAGE(sA, 0,  0,     0, 1);
    STAGE(sBcur, 0,  65536, 0, 0);
    STAGE(sBcur, 0,  65536, 0, 1);
    STAGE(sBcur, 64, 65536, 1, 0);
    STAGE(sBcur, 64, 65536, 1, 1);
    VM4;
    BAR;

    for (int t = 0; t < 8; ++t) {
        const __bf16* sBnext = (t < 7) ? (sBcur + 131072) : sBcur;

#pragma unroll
        for (int f = 0; f < 4; ++f) {
            const __bf16* bp = (f == 3) ? sBnext : sBcur;
            const int ka0 = (2 * f + 1) * 64;            // A k-part 2f+1 -> d1
            const int ka1 = (((2 * f + 2) & 7)) * 64;    // A k-part 2f+2 -> d0
            const int kb0 = (((2 * f + 2) & 7)) * 64;    // B k-part 2f+2 -> d0
            const int kb1 = (((2 * f + 3) & 7)) * 64;    // B k-part 2f+3 -> d1
            PHASE(0, 0, true,  STAGE(sA, ka0, 0,     1, 0), VMNONE);
            PHASE(0, 1, false, STAGE(sA, ka0, 0,     1, 1), VMNONE);
            PHASE(0, 2, false, STAGE(bp, kb0, 65536, 0, 0), VMNONE);
            PHASE(0, 3, false, STAGE(bp, kb0, 65536, 0, 1), VM4);
            PHASE(1, 0, true,  STAGE(sA, ka1, 0,     0, 0), VMNONE);
            PHASE(1, 1, false, STAGE(sA, ka1, 0,     0, 1), VMNONE);
            PHASE(1, 2, false, STAGE(bp, kb1, 65536, 1, 0), VMNONE);
            PHASE(1, 3, false, STAGE(bp, kb1, 65536, 1, 1), VM4);
        }

        // ---- per-tile epilogue: pure VALU + 4 scalar-ish loads, no barrier
        const int tmBase = (tmQ * 8 + t) * 256;
        float cv[4];
#pragma unroll
        for (int cb = 0; cb < 4; ++cb) cv[cb] = cw[tmBase + wc * 64 + cb * 16 + lcol];
#pragma unroll
        for (int rb = 0; rb < 8; ++rb)
#pragma unroll
            for (int i2 = 0; i2 < 4; ++i2) {
                float s = rowsum[rb][i2];
#pragma unroll
                for (int cb = 0; cb < 4; ++cb)
                    s += __expf(0.004f * acc[rb][cb][i2]) * cv[cb];
                rowsum[rb][i2] = s;
            }
#pragma unroll
        for (int rb = 0; rb < 8; ++rb)
#pragma unroll
            for (int cb = 0; cb < 4; ++cb)
                acc[rb][cb] = (f32x4){0.f, 0.f, 0.f, 0.f};

        sBcur = sBnext;
    }

    // ---- final: 16-lane reduce + one atomic per (block, n)
#pragma unroll
    for (int rb = 0; rb < 8; ++rb)
#pragma unroll
        for (int i2 = 0; i2 < 4; ++i2) {
            float s = rowsum[rb][i2];
#pragma unroll
            for (int off = 1; off < 16; off <<= 1) s += __shfl_xor(s, off, 64);
            if (lcol == 0) {
                const int n = tnBase + wr * 128 + rb * 16 + lrow * 4 + i2;
                atomicAdd(&out[n], ex[n] * s);
            }
        }
}

extern "C" void kernel_launch(void* const* d_in, const int* in_sizes, int n_in,
                              void* d_out, int out_size, void* d_ws, size_t ws_size,
                              hipStream_t stream) {
    const float* X = (const float*)d_in[0];   // 16384 x 512
    const float* Y = (const float*)d_in[1];   //  8192 x 512
    const float* W = (const float*)d_in[2];   // 8192
    const float* b = (const float*)d_in[3];   // 1
    float* out = (float*)d_out;               // 16384

    char* ws = (char*)d_ws;
    __bf16* Xb = (__bf16*)(ws);
    __bf16* Yb = (__bf16*)(ws + 16777216);
    float*  ex = (float*)(ws + 16777216 + 8388608);
    float*  cw = (float*)(ws + 16777216 + 8388608 + 65536);

    prep_kernel<<<4096, 256, 0, stream>>>(X, Xb, ex, nullptr, 16384);
    prep_kernel<<<2048, 256, 0, stream>>>(Y, Yb, cw, W, 8192);
    init_out<<<64, 256, 0, stream>>>(out, b, 16384);
    rbf_gemm<<<256, 512, 0, stream>>>(Xb, Yb, ex, cw, out);
}

// Round 5
// 180.922 us; speedup vs baseline: 1.4314x; 1.4314x over previous
//
#include <hip/hip_runtime.h>
#include <hip/hip_bf16.h>

// out[n] = b + e_x[n] * sum_m exp(2*GAMMA*dot(x_n,y_m)) * c[m]
// n=16384, m=8192, d=512.
// Round 5: A-RESIDENT GEMM. Diagnosis from r4: FETCH=328MB vs 24MB unique ->
// all staging missed L2 -> latency-bound. Fix: keep the block's whole A panel
// (128 rows x 512 K = 128KB) resident in LDS (staged once), stream only B in
// 16KB double-buffered chunks (LDS = 160KB exactly). Each XCD's 32 blocks
// share one 4MB B-half -> B is L2-resident. Minimal 2-phase chunk loop.
//
// Workspace: Xb bf16[16384*512] @0, Yb bf16[8192*512] @16777216,
//            ex f32[16384] @25165824, cw f32[8192] @25231360.

#define GAMMA 0.002f

typedef __bf16 bf16x8 __attribute__((ext_vector_type(8)));
typedef float  f32x4  __attribute__((ext_vector_type(4)));
typedef __attribute__((address_space(3))) void lds_void_t;
typedef __attribute__((address_space(1))) const void gl_void_t;

// ---------------- prep: f32 -> bf16 + exp(-gamma*||row||^2) (xW==nullptr)
// or c[m] = exp(-gamma*||row||^2)*W[m]
__global__ __launch_bounds__(256) void prep_kernel(const float* __restrict__ src,
                                                   __bf16* __restrict__ dst,
                                                   float* __restrict__ fac,
                                                   const float* __restrict__ xW,
                                                   int nrows) {
    const int wid  = threadIdx.x >> 6;
    const int lane = threadIdx.x & 63;
    const int row  = blockIdx.x * 4 + wid;
    if (row >= nrows) return;
    const float4* s = reinterpret_cast<const float4*>(src + (size_t)row * 512);
    float4 v0 = s[lane * 2];
    float4 v1 = s[lane * 2 + 1];
    float acc = v0.x * v0.x + v0.y * v0.y + v0.z * v0.z + v0.w * v0.w
              + v1.x * v1.x + v1.y * v1.y + v1.z * v1.z + v1.w * v1.w;
    bf16x8 o;
    o[0] = (__bf16)v0.x; o[1] = (__bf16)v0.y; o[2] = (__bf16)v0.z; o[3] = (__bf16)v0.w;
    o[4] = (__bf16)v1.x; o[5] = (__bf16)v1.y; o[6] = (__bf16)v1.z; o[7] = (__bf16)v1.w;
    *reinterpret_cast<bf16x8*>(dst + (size_t)row * 512 + lane * 8) = o;
#pragma unroll
    for (int off = 32; off >= 1; off >>= 1) acc += __shfl_xor(acc, off, 64);
    if (lane == 0) {
        float e = __expf(-GAMMA * acc);
        fac[row] = xW ? e * xW[row] : e;
    }
}

__global__ void init_out(float* __restrict__ out, const float* __restrict__ b, int n) {
    int i = blockIdx.x * blockDim.x + threadIdx.x;
    if (i < n) out[i] = b[0];
}

// ---------------- LDS geometry ----------------
// lA [128 rows][512 k] bf16 @ 0 (131072 B, row stride 1024B), resident all kernel.
// lB [2 dbuf][128 cols][64 k] bf16 @ 131072 (2 x 16384 B, row stride 128B).
// Granule swizzle (both arrays): 16B granule g of row r stored at slot g^(r&7);
// staged linearly via pre-swizzled global source (rule #21), read with same XOR.
// -> uniform 8 lanes per 16B bank-column per ds_read_b128 = conflict-free.

// grid: 256 blocks (1/CU), 512 threads (8 waves, 2r x 4c).
__global__ __launch_bounds__(512, 2) void rbf_gemm(
    const __bf16* __restrict__ Xb, const __bf16* __restrict__ Yb,
    const float* __restrict__ ex, const float* __restrict__ cw,
    float* __restrict__ out) {
    __shared__ __align__(128) char smem[163840];

    const int tid  = threadIdx.x;
    const int wid  = tid >> 6;
    const int lane = tid & 63;
    const int wr   = wid >> 2;      // 0..1: row half (64 rows)
    const int wc   = wid & 3;       // 0..3: col quarter (32 cols)

    // Block -> (row group, col half), XCD-aware: XCD x hosts one contiguous
    // rg-quarter and ONE col-half -> per-XCD B working set = 4MB (L2-resident).
    const int pid = blockIdx.x;
    const int xcd = pid & 7;
    const int j   = pid >> 3;                  // 0..31
    const int ch  = xcd & 1;                   // col half
    const int rg  = (xcd >> 1) * 32 + j;       // 0..127 row group
    const int rowBase = rg * 128;
    const int colBase = ch * 4096;

    // ds_read per-lane bases
    const int rl  = lane & 15;
    const int cg0 = (((lane >> 4) ^ (lane & 7)) & 7) * 16;  // swizzled granule, ks=0
    const int aRd = (wr * 64 + rl) * 1024 + cg0;
    const int bRd = 131072 + (wc * 32 + rl) * 128 + cg0;

    // B staging: per-lane pre-swizzled global offset (elems); wave stages 16 cols.
    const int gOffB = (lane >> 3) * 512 + (((lane & 7) ^ (lane >> 3)) * 8);
    const __bf16* sBw = Yb + (size_t)(colBase + wid * 16) * 512 + gOffB;

    // ---- prologue: stage whole A panel (1 row per load, swizzled src) + B chunk 0
    {
        const size_t arow0 = (size_t)(rowBase + wid * 16) * 512;
#pragma unroll
        for (int i = 0; i < 16; ++i) {
            const __bf16* src = Xb + arow0 + (size_t)i * 512 + ((lane ^ (i & 7)) * 8);
            __builtin_amdgcn_global_load_lds((gl_void_t*)src,
                (lds_void_t*)(smem + (wid * 16 + i) * 1024), 16, 0, 0);
        }
#pragma unroll
        for (int jj = 0; jj < 2; ++jj)
            __builtin_amdgcn_global_load_lds((gl_void_t*)(sBw + jj * 4096),
                (lds_void_t*)(smem + 131072 + wid * 2048 + jj * 1024), 16, 0, 0);
    }
    asm volatile("s_waitcnt vmcnt(0)");
    __builtin_amdgcn_s_barrier();

    f32x4 acc[4][2] = {};
    float rowsum[4][4] = {};
    const int lcol = lane & 15, lrow = lane >> 4;

    // ---- main loop: 256 chunks = 32 col-panels x 8 K-chunks (K accumulates
    // within a panel; epilogue at chunk 7 consumes full-K acc).
#pragma unroll 2
    for (int c = 0; c < 256; ++c) {
        const int buf = (c & 1) * 16384;
        // stage chunk c+1 into the other buffer (readers of it finished last iter)
        if (c < 255) {
            const int c1 = c + 1;
            const size_t soff = (size_t)(c1 >> 3) * 65536 + (size_t)(c1 & 7) * 64;
            const int dst = 131072 + ((c1 & 1) * 16384) + wid * 2048;
#pragma unroll
            for (int jj = 0; jj < 2; ++jj)
                __builtin_amdgcn_global_load_lds((gl_void_t*)(sBw + soff + jj * 4096),
                    (lds_void_t*)(smem + dst + jj * 1024), 16, 0, 0);
        }

        const int kc = (c & 7) * 128;   // byte offset of K-chunk within A row
        bf16x8 af[4][2], bfv[2][2];
#pragma unroll
        for (int rb = 0; rb < 4; ++rb)
#pragma unroll
            for (int ks = 0; ks < 2; ++ks)
                af[rb][ks] = *reinterpret_cast<const bf16x8*>(
                    &smem[(aRd + rb * 16384 + kc) ^ (ks * 64)]);
#pragma unroll
        for (int cb = 0; cb < 2; ++cb)
#pragma unroll
            for (int ks = 0; ks < 2; ++ks)
                bfv[cb][ks] = *reinterpret_cast<const bf16x8*>(
                    &smem[(bRd + buf + cb * 2048) ^ (ks * 64)]);

        __builtin_amdgcn_s_setprio(1);
#pragma unroll
        for (int ks = 0; ks < 2; ++ks)
#pragma unroll
            for (int rb = 0; rb < 4; ++rb)
#pragma unroll
                for (int cb = 0; cb < 2; ++cb)
                    acc[rb][cb] = __builtin_amdgcn_mfma_f32_16x16x32_bf16(
                        af[rb][ks], bfv[cb][ks], acc[rb][cb], 0, 0, 0);
        __builtin_amdgcn_s_setprio(0);

        // per-panel epilogue: acc now holds full K=512 dot for 64r x 32c
        if ((c & 7) == 7) {
            const int p = c >> 3;
            const float cv0 = cw[colBase + p * 128 + wc * 32 + lcol];
            const float cv1 = cw[colBase + p * 128 + wc * 32 + 16 + lcol];
#pragma unroll
            for (int rb = 0; rb < 4; ++rb)
#pragma unroll
                for (int i2 = 0; i2 < 4; ++i2)
                    rowsum[rb][i2] += __expf(0.004f * acc[rb][0][i2]) * cv0
                                    + __expf(0.004f * acc[rb][1][i2]) * cv1;
#pragma unroll
            for (int rb = 0; rb < 4; ++rb) {
                acc[rb][0] = (f32x4){0.f, 0.f, 0.f, 0.f};
                acc[rb][1] = (f32x4){0.f, 0.f, 0.f, 0.f};
            }
        }

        asm volatile("s_waitcnt vmcnt(0)");   // stage issued ~full chunk earlier
        __builtin_amdgcn_s_barrier();
    }

    // ---- final: 16-lane reduce + one atomic per (wave, n); out pre-init'd to b
#pragma unroll
    for (int rb = 0; rb < 4; ++rb)
#pragma unroll
        for (int i2 = 0; i2 < 4; ++i2) {
            float s = rowsum[rb][i2];
#pragma unroll
            for (int off = 1; off < 16; off <<= 1) s += __shfl_xor(s, off, 64);
            if (lcol == 0) {
                const int n = rowBase + wr * 64 + rb * 16 + lrow * 4 + i2;
                atomicAdd(&out[n], ex[n] * s);
            }
        }
}

extern "C" void kernel_launch(void* const* d_in, const int* in_sizes, int n_in,
                              void* d_out, int out_size, void* d_ws, size_t ws_size,
                              hipStream_t stream) {
    const float* X = (const float*)d_in[0];   // 16384 x 512
    const float* Y = (const float*)d_in[1];   //  8192 x 512
    const float* W = (const float*)d_in[2];   // 8192
    const float* b = (const float*)d_in[3];   // 1
    float* out = (float*)d_out;               // 16384

    char* ws = (char*)d_ws;
    __bf16* Xb = (__bf16*)(ws);
    __bf16* Yb = (__bf16*)(ws + 16777216);
    float*  ex = (float*)(ws + 16777216 + 8388608);
    float*  cw = (float*)(ws + 16777216 + 8388608 + 65536);

    prep_kernel<<<4096, 256, 0, stream>>>(X, Xb, ex, nullptr, 16384);
    prep_kernel<<<2048, 256, 0, stream>>>(Y, Yb, cw, W, 8192);
    init_out<<<64, 256, 0, stream>>>(out, b, 16384);
    rbf_gemm<<<256, 512, 0, stream>>>(Xb, Yb, ex, cw, out);
}